// Round 1
// baseline (54.394 us; speedup 1.0000x reference)
//
#include <hip/hip_runtime.h>

namespace {

constexpr int kBatch  = 8192;
constexpr int kHidden = 4096;
constexpr int kSeeds  = 32;
constexpr int kChunk  = 128;
constexpr int kTpb    = 256;

// Each thread owns 4 float4 column slots: col4 = t + j*256, j=0..3.
// Element column = 4*(t + j*256)  ->  seed s = (t>>5) + 8*j (fixed per thread),
// chunk offset c = 4*(t&31) (fixed per thread). So blend coefficients and
// per-seed partial sums live in statically-indexed registers.
__global__ __launch_bounds__(kTpb) void kasmina_main(
    const float* __restrict__ x,
    const int*   __restrict__ life,
    const int*   __restrict__ bid,
    const int*   __restrict__ strat,
    const float* __restrict__ alpha,
    const float* __restrict__ bw,
    float*       __restrict__ out,
    float*       __restrict__ psum,
    float*       __restrict__ psumsq)
{
    const int t  = threadIdx.x;
    const int c0 = (t & 31) * 4;

    float4 mcoef[4];
    float4 acoef[4];
    float  ssum[4];
    float  ssq[4];

    #pragma unroll
    for (int j = 0; j < 4; ++j) {
        const int   s  = (t >> 5) + j * 8;
        const int   lf = life[s];
        const bool  act = (lf >= 3) && (lf <= 6);
        const int   st = strat[s];
        const float al = alpha[s];
        const float4 w = *reinterpret_cast<const float4*>(
            &bw[bid[s] * kHidden + s * kChunk + c0]);

        float4 mm = make_float4(1.f, 1.f, 1.f, 1.f);
        float4 aa = make_float4(0.f, 0.f, 0.f, 0.f);
        if (act) {
            if (st == 0) {
                const float om = 1.f - al;
                mm = make_float4(fmaf(al, w.x, om), fmaf(al, w.y, om),
                                 fmaf(al, w.z, om), fmaf(al, w.w, om));
            } else if (st == 1) {
                mm = w;
            } else {
                aa = w;
            }
        }
        mcoef[j] = mm;
        acoef[j] = aa;
        ssum[j]  = 0.f;
        ssq[j]   = 0.f;
    }

    for (int r = blockIdx.x; r < kBatch; r += gridDim.x) {
        const float4* __restrict__ xrow =
            reinterpret_cast<const float4*>(x + (size_t)r * kHidden);
        float4* __restrict__ orow =
            reinterpret_cast<float4*>(out + (size_t)r * kHidden);
        #pragma unroll
        for (int j = 0; j < 4; ++j) {
            const int idx = t + j * kTpb;
            const float4 xv = xrow[idx];
            float4 ov;
            ov.x = fmaf(mcoef[j].x, xv.x, acoef[j].x);
            ov.y = fmaf(mcoef[j].y, xv.y, acoef[j].y);
            ov.z = fmaf(mcoef[j].z, xv.z, acoef[j].z);
            ov.w = fmaf(mcoef[j].w, xv.w, acoef[j].w);
            orow[idx] = ov;
            ssum[j] += (xv.x + xv.y) + (xv.z + xv.w);
            ssq[j]  = fmaf(xv.x, xv.x, ssq[j]);
            ssq[j]  = fmaf(xv.y, xv.y, ssq[j]);
            ssq[j]  = fmaf(xv.z, xv.z, ssq[j]);
            ssq[j]  = fmaf(xv.w, xv.w, ssq[j]);
        }
    }

    // 32-lane group reduce (lanes sharing t>>5 have the same seed); offsets
    // 1..16 under xor stay within each 32-lane half of the wave64.
    #pragma unroll
    for (int j = 0; j < 4; ++j) {
        float a = ssum[j];
        float b = ssq[j];
        #pragma unroll
        for (int off = 1; off < 32; off <<= 1) {
            a += __shfl_xor(a, off, 64);
            b += __shfl_xor(b, off, 64);
        }
        if ((t & 31) == 0) {
            const int s = (t >> 5) + j * 8;  // each (wave, half, j) -> unique seed per block
            psum[blockIdx.x * kSeeds + s]   = a;
            psumsq[blockIdx.x * kSeeds + s] = b;
        }
    }
}

// One block per seed; deterministic final reduce over per-block partials.
__global__ __launch_bounds__(kTpb) void kasmina_reduce(
    const float* __restrict__ psum,
    const float* __restrict__ psumsq,
    float*       __restrict__ tail,   // d_out + B*H: [tsum(32) | tsumsq(32) | tcount(32)]
    int nblk)
{
    const int s = blockIdx.x;
    const int t = threadIdx.x;
    float a = 0.f, b = 0.f;
    for (int blk = t; blk < nblk; blk += kTpb) {
        a += psum[(size_t)blk * kSeeds + s];
        b += psumsq[(size_t)blk * kSeeds + s];
    }
    #pragma unroll
    for (int off = 1; off < 64; off <<= 1) {
        a += __shfl_xor(a, off, 64);
        b += __shfl_xor(b, off, 64);
    }
    __shared__ float la[4], lb[4];
    if ((t & 63) == 0) { la[t >> 6] = a; lb[t >> 6] = b; }
    __syncthreads();
    if (t == 0) {
        a = (la[0] + la[1]) + (la[2] + la[3]);
        b = (lb[0] + lb[1]) + (lb[2] + lb[3]);
        tail[s]             = a;
        tail[kSeeds + s]    = b;
        tail[2 * kSeeds + s] = (float)(kBatch * kChunk);  // 1048576.0f
    }
}

}  // namespace

extern "C" void kernel_launch(void* const* d_in, const int* in_sizes, int n_in,
                              void* d_out, int out_size, void* d_ws, size_t ws_size,
                              hipStream_t stream) {
    const float* x     = (const float*)d_in[0];
    const int*   life  = (const int*)d_in[1];
    const int*   bid   = (const int*)d_in[2];
    const int*   strat = (const int*)d_in[3];
    const float* alpha = (const float*)d_in[4];
    const float* bw    = (const float*)d_in[5];
    float*       out   = (float*)d_out;

    int nblk = 1024;  // 8 rows/block; 4096 waves -> 16 waves/CU
    const size_t per_blk = (size_t)kSeeds * 2 * sizeof(float);
    if ((size_t)nblk * per_blk > ws_size) {
        nblk = (int)(ws_size / per_blk);
        if (nblk < 1) nblk = 1;
    }
    float* psum   = (float*)d_ws;
    float* psumsq = psum + (size_t)nblk * kSeeds;

    kasmina_main<<<nblk, kTpb, 0, stream>>>(x, life, bid, strat, alpha, bw,
                                            out, psum, psumsq);

    float* tail = out + (size_t)kBatch * kHidden;
    kasmina_reduce<<<kSeeds, kTpb, 0, stream>>>(psum, psumsq, tail, nblk);
}

// Round 2
// 53.064 us; speedup vs baseline: 1.0251x; 1.0251x over previous
//
#include <hip/hip_runtime.h>

namespace {

constexpr int kBatch  = 8192;
constexpr int kHidden = 4096;
constexpr int kSeeds  = 32;
constexpr int kChunk  = 128;
constexpr int kTpb    = 256;

typedef float fvec4 __attribute__((ext_vector_type(4)));

// Each thread owns 4 float4 column slots: col4 = t + j*256, j=0..3.
// Element column = 4*(t + j*256)  ->  seed s = (t>>5) + 8*j (fixed per thread),
// chunk offset c = 4*(t&31) (fixed per thread). So blend coefficients and
// per-seed partial sums live in statically-indexed registers.
__global__ __launch_bounds__(kTpb) void kasmina_main(
    const float* __restrict__ x,
    const int*   __restrict__ life,
    const int*   __restrict__ bid,
    const int*   __restrict__ strat,
    const float* __restrict__ alpha,
    const float* __restrict__ bw,
    float*       __restrict__ out,
    float*       __restrict__ psum,
    float*       __restrict__ psumsq)
{
    const int t  = threadIdx.x;
    const int c0 = (t & 31) * 4;

    fvec4 mcoef[4];
    fvec4 acoef[4];
    float ssum[4];
    float ssq[4];

    #pragma unroll
    for (int j = 0; j < 4; ++j) {
        const int   s   = (t >> 5) + j * 8;
        const int   lf  = life[s];
        const bool  act = (lf >= 3) && (lf <= 6);
        const int   st  = strat[s];
        const float al  = alpha[s];
        const fvec4 w = *reinterpret_cast<const fvec4*>(
            &bw[bid[s] * kHidden + s * kChunk + c0]);

        fvec4 mm = {1.f, 1.f, 1.f, 1.f};
        fvec4 aa = {0.f, 0.f, 0.f, 0.f};
        if (act) {
            if (st == 0) {
                const float om = 1.f - al;
                mm = al * w + om;
            } else if (st == 1) {
                mm = w;
            } else {
                aa = w;
            }
        }
        mcoef[j] = mm;
        acoef[j] = aa;
        ssum[j]  = 0.f;
        ssq[j]   = 0.f;
    }

    for (int r = blockIdx.x; r < kBatch; r += gridDim.x) {
        const fvec4* __restrict__ xrow =
            reinterpret_cast<const fvec4*>(x + (size_t)r * kHidden);
        fvec4* __restrict__ orow =
            reinterpret_cast<fvec4*>(out + (size_t)r * kHidden);
        #pragma unroll
        for (int j = 0; j < 4; ++j) {
            const int idx = t + j * kTpb;
            const fvec4 xv = xrow[idx];
            fvec4 ov;
            ov.x = fmaf(mcoef[j].x, xv.x, acoef[j].x);
            ov.y = fmaf(mcoef[j].y, xv.y, acoef[j].y);
            ov.z = fmaf(mcoef[j].z, xv.z, acoef[j].z);
            ov.w = fmaf(mcoef[j].w, xv.w, acoef[j].w);
            // Non-temporal: write stream must not evict x from L2/L3.
            __builtin_nontemporal_store(ov, &orow[idx]);
            ssum[j] += (xv.x + xv.y) + (xv.z + xv.w);
            ssq[j]  = fmaf(xv.x, xv.x, ssq[j]);
            ssq[j]  = fmaf(xv.y, xv.y, ssq[j]);
            ssq[j]  = fmaf(xv.z, xv.z, ssq[j]);
            ssq[j]  = fmaf(xv.w, xv.w, ssq[j]);
        }
    }

    // 32-lane group reduce (lanes sharing t>>5 have the same seed); offsets
    // 1..16 under xor stay within each 32-lane half of the wave64.
    #pragma unroll
    for (int j = 0; j < 4; ++j) {
        float a = ssum[j];
        float b = ssq[j];
        #pragma unroll
        for (int off = 1; off < 32; off <<= 1) {
            a += __shfl_xor(a, off, 64);
            b += __shfl_xor(b, off, 64);
        }
        if ((t & 31) == 0) {
            const int s = (t >> 5) + j * 8;  // each (wave, half, j) -> unique seed per block
            psum[blockIdx.x * kSeeds + s]   = a;
            psumsq[blockIdx.x * kSeeds + s] = b;
        }
    }
}

// One block per seed; deterministic final reduce over per-block partials.
__global__ __launch_bounds__(kTpb) void kasmina_reduce(
    const float* __restrict__ psum,
    const float* __restrict__ psumsq,
    float*       __restrict__ tail,   // d_out + B*H: [tsum(32) | tsumsq(32) | tcount(32)]
    int nblk)
{
    const int s = blockIdx.x;
    const int t = threadIdx.x;
    float a = 0.f, b = 0.f;
    for (int blk = t; blk < nblk; blk += kTpb) {
        a += psum[(size_t)blk * kSeeds + s];
        b += psumsq[(size_t)blk * kSeeds + s];
    }
    #pragma unroll
    for (int off = 1; off < 64; off <<= 1) {
        a += __shfl_xor(a, off, 64);
        b += __shfl_xor(b, off, 64);
    }
    __shared__ float la[4], lb[4];
    if ((t & 63) == 0) { la[t >> 6] = a; lb[t >> 6] = b; }
    __syncthreads();
    if (t == 0) {
        a = (la[0] + la[1]) + (la[2] + la[3]);
        b = (lb[0] + lb[1]) + (lb[2] + lb[3]);
        tail[s]              = a;
        tail[kSeeds + s]     = b;
        tail[2 * kSeeds + s] = (float)(kBatch * kChunk);  // 1048576.0f
    }
}

}  // namespace

extern "C" void kernel_launch(void* const* d_in, const int* in_sizes, int n_in,
                              void* d_out, int out_size, void* d_ws, size_t ws_size,
                              hipStream_t stream) {
    const float* x     = (const float*)d_in[0];
    const int*   life  = (const int*)d_in[1];
    const int*   bid   = (const int*)d_in[2];
    const int*   strat = (const int*)d_in[3];
    const float* alpha = (const float*)d_in[4];
    const float* bw    = (const float*)d_in[5];
    float*       out   = (float*)d_out;

    int nblk = 2048;  // 4 rows/block; 8 blocks/CU -> 32 waves/CU
    const size_t per_blk = (size_t)kSeeds * 2 * sizeof(float);
    if ((size_t)nblk * per_blk > ws_size) {
        nblk = (int)(ws_size / per_blk);
        if (nblk < 1) nblk = 1;
    }
    float* psum   = (float*)d_ws;
    float* psumsq = psum + (size_t)nblk * kSeeds;

    kasmina_main<<<nblk, kTpb, 0, stream>>>(x, life, bid, strat, alpha, bw,
                                            out, psum, psumsq);

    float* tail = out + (size_t)kBatch * kHidden;
    kasmina_reduce<<<kSeeds, kTpb, 0, stream>>>(psum, psumsq, tail, nblk);
}

// Round 3
// 49.542 us; speedup vs baseline: 1.0979x; 1.0711x over previous
//
#include <hip/hip_runtime.h>

namespace {

constexpr int kBatch  = 8192;
constexpr int kHidden = 4096;
constexpr int kSeeds  = 32;
constexpr int kChunk  = 128;
constexpr int kTpb    = 1024;   // one float4 column slot per thread (4096/4 = 1024)
constexpr int kBlocks = 512;    // 16 contiguous rows per block
constexpr int kRowsPerBlk = kBatch / kBlocks;

typedef float fvec4 __attribute__((ext_vector_type(4)));

// Thread t owns column quad t: elements 4t..4t+3 -> seed s = t>>5 (fixed),
// chunk offset c = 4*(t&31). Blend is out = m*x + a with per-thread constant
// (m,a) registers. Each block streams 16 contiguous rows (256 KB in, 256 KB
// out); loads are batched 4 rows ahead of the dependent FMA/store.
__global__ __launch_bounds__(kTpb) void kasmina_main(
    const float* __restrict__ x,
    const int*   __restrict__ life,
    const int*   __restrict__ bid,
    const int*   __restrict__ strat,
    const float* __restrict__ alpha,
    const float* __restrict__ bw,
    float*       __restrict__ out,
    float*       __restrict__ psum,    // [kSeeds][kBlocks] transposed layout
    float*       __restrict__ psumsq)  // [kSeeds][kBlocks]
{
    const int t  = threadIdx.x;
    const int s  = t >> 5;
    const int c0 = (t & 31) * 4;

    const int   lf  = life[s];
    const bool  act = (lf >= 3) && (lf <= 6);
    const int   st  = strat[s];
    const float al  = alpha[s];
    const fvec4 w   = *reinterpret_cast<const fvec4*>(
        &bw[bid[s] * kHidden + s * kChunk + c0]);

    fvec4 mm = {1.f, 1.f, 1.f, 1.f};
    fvec4 aa = {0.f, 0.f, 0.f, 0.f};
    if (act) {
        if (st == 0) {
            mm = al * w + (1.f - al);
        } else if (st == 1) {
            mm = w;
        } else {
            aa = w;
        }
    }

    float ssum = 0.f;
    float ssq  = 0.f;

    const int r0 = blockIdx.x * kRowsPerBlk;
    const float* __restrict__ xbase = x   + (size_t)r0 * kHidden + 4 * t;
    float*       __restrict__ obase = out + (size_t)r0 * kHidden + 4 * t;

    #pragma unroll
    for (int rc = 0; rc < kRowsPerBlk; rc += 4) {
        fvec4 xv[4];
        #pragma unroll
        for (int k = 0; k < 4; ++k)
            xv[k] = *reinterpret_cast<const fvec4*>(
                xbase + (size_t)(rc + k) * kHidden);
        #pragma unroll
        for (int k = 0; k < 4; ++k) {
            fvec4 ov;
            ov.x = fmaf(mm.x, xv[k].x, aa.x);
            ov.y = fmaf(mm.y, xv[k].y, aa.y);
            ov.z = fmaf(mm.z, xv[k].z, aa.z);
            ov.w = fmaf(mm.w, xv[k].w, aa.w);
            __builtin_nontemporal_store(
                ov, reinterpret_cast<fvec4*>(obase + (size_t)(rc + k) * kHidden));
            ssum += (xv[k].x + xv[k].y) + (xv[k].z + xv[k].w);
            ssq   = fmaf(xv[k].x, xv[k].x, ssq);
            ssq   = fmaf(xv[k].y, xv[k].y, ssq);
            ssq   = fmaf(xv[k].z, xv[k].z, ssq);
            ssq   = fmaf(xv[k].w, xv[k].w, ssq);
        }
    }

    // 32-lane group reduce: lanes t..t+31 (same t>>5) share one seed; xor
    // offsets 1..16 stay within each 32-lane half of the wave64.
    #pragma unroll
    for (int off = 1; off < 32; off <<= 1) {
        ssum += __shfl_xor(ssum, off, 64);
        ssq  += __shfl_xor(ssq,  off, 64);
    }
    if ((t & 31) == 0) {
        psum[s * kBlocks + blockIdx.x]   = ssum;
        psumsq[s * kBlocks + blockIdx.x] = ssq;
    }
}

// One wave per seed; coalesced reads over the transposed partial layout.
__global__ __launch_bounds__(64) void kasmina_reduce(
    const float* __restrict__ psum,
    const float* __restrict__ psumsq,
    float*       __restrict__ tail,   // d_out + B*H: [tsum(32) | tsumsq(32) | tcount(32)]
    int nblk)
{
    const int s = blockIdx.x;
    const int t = threadIdx.x;
    float a = 0.f, b = 0.f;
    for (int i = t; i < nblk; i += 64) {
        a += psum[(size_t)s * nblk + i];
        b += psumsq[(size_t)s * nblk + i];
    }
    #pragma unroll
    for (int off = 1; off < 64; off <<= 1) {
        a += __shfl_xor(a, off, 64);
        b += __shfl_xor(b, off, 64);
    }
    if (t == 0) {
        tail[s]              = a;
        tail[kSeeds + s]     = b;
        tail[2 * kSeeds + s] = (float)(kBatch * kChunk);  // 1048576.0f
    }
}

}  // namespace

extern "C" void kernel_launch(void* const* d_in, const int* in_sizes, int n_in,
                              void* d_out, int out_size, void* d_ws, size_t ws_size,
                              hipStream_t stream) {
    const float* x     = (const float*)d_in[0];
    const int*   life  = (const int*)d_in[1];
    const int*   bid   = (const int*)d_in[2];
    const int*   strat = (const int*)d_in[3];
    const float* alpha = (const float*)d_in[4];
    const float* bw    = (const float*)d_in[5];
    float*       out   = (float*)d_out;

    float* psum   = (float*)d_ws;                      // [32][512]
    float* psumsq = psum + (size_t)kSeeds * kBlocks;   // needs 128 KB total

    kasmina_main<<<kBlocks, kTpb, 0, stream>>>(x, life, bid, strat, alpha, bw,
                                               out, psum, psumsq);

    float* tail = out + (size_t)kBatch * kHidden;
    kasmina_reduce<<<kSeeds, 64, 0, stream>>>(psum, psumsq, tail, kBlocks);
}